// Round 1
// baseline (604.085 us; speedup 1.0000x reference)
//
#include <hip/hip_runtime.h>
#include <hip/hip_cooperative_groups.h>
#include <math.h>

namespace cg = cooperative_groups;

// Problem constants (fixed by the reference):
#define W_    1024              // layer width
#define NL_   8                 // layers (7 matvecs)
#define NTOT_ (W_ * NL_)        // 8192
#define RS_   (NTOT_ + 1)       // params row stride = 8193 floats (bias in col 8192)

// Dot of one weight row segment (1024 cols) against h[] (LDS), wave-wide.
// lane i covers columns i, i+64, ..., i+960: fully coalesced dword loads.
// (float4 is impossible: row base offset = (l*1024+row)*8193*4 B, 16B-aligned
// only when row%4==0.)
__device__ __forceinline__ float dot_row(const float* __restrict__ params,
                                         const float* __restrict__ h,
                                         int l, int row, int lane) {
    const float* wrow = params + (size_t)(l * W_ + row) * RS_ + (size_t)(l - 1) * W_;
    float acc = 0.f;
#pragma unroll
    for (int i = 0; i < 16; ++i)
        acc += wrow[lane + 64 * i] * h[lane + 64 * i];
    // wave-64 butterfly reduce
#pragma unroll
    for (int off = 32; off; off >>= 1)
        acc += __shfl_down(acc, off);
    return acc;
}

// Persistent cooperative kernel: 256 blocks x 256 threads = 1024 waves,
// one wave per output neuron per layer. grid.sync() between layers.
__global__ __launch_bounds__(256)
void mlp_fused(const float* __restrict__ x, const float* __restrict__ params,
               float* __restrict__ out, float* __restrict__ ws) {
    cg::grid_group grid = cg::this_grid();
    __shared__ float h[W_];

    const int tid  = threadIdx.x;
    const int lane = tid & 63;
    const int wave = tid >> 6;                 // 0..3
    const int row  = blockIdx.x * 4 + wave;    // 0..1023

    float* buf0 = ws;          // ping-pong activation buffers (d_ws is
    float* buf1 = ws + W_;     // re-poisoned 0xAA each call; we fully init)

    // init: values[0:W] = x
    const int g = blockIdx.x * 256 + tid;
    if (g < W_) buf0[g] = x[g];
    grid.sync();

    float* cur = buf0;
    float* nxt = buf1;

    for (int l = 1; l < NL_; ++l) {
        // stage current activations (4 KB) into LDS, 4 coalesced loads/thread
#pragma unroll
        for (int i = 0; i < W_ / 256; ++i)
            h[tid + 256 * i] = cur[tid + 256 * i];
        __syncthreads();

        float acc = dot_row(params, h, l, row, lane);

        if (lane == 0) {
            float pre = acc + params[(size_t)(l * W_ + row) * RS_ + NTOT_]; // bias
            float v = (l == NL_ - 1) ? pre                     // output: identity
                                     : pre / (1.f + __expf(-pre)); // silu
            if (l == NL_ - 1) out[row] = v;
            else              nxt[row] = v;
        }

        float* t = cur; cur = nxt; nxt = t;
        if (l != NL_ - 1) grid.sync();  // publishes nxt + guards LDS h reuse
    }
}

// ---- fallback path (only if cooperative launch is rejected) ----
__global__ void init_vals(const float* __restrict__ x, float* __restrict__ buf) {
    int g = blockIdx.x * blockDim.x + threadIdx.x;
    if (g < W_) buf[g] = x[g];
}

__global__ __launch_bounds__(256)
void mlp_layer(const float* __restrict__ params, const float* __restrict__ in,
               float* __restrict__ outv, int l) {
    __shared__ float h[W_];
    const int tid  = threadIdx.x;
    const int lane = tid & 63;
    const int wave = tid >> 6;
    const int row  = blockIdx.x * 4 + wave;
#pragma unroll
    for (int i = 0; i < W_ / 256; ++i)
        h[tid + 256 * i] = in[tid + 256 * i];
    __syncthreads();
    float acc = dot_row(params, h, l, row, lane);
    if (lane == 0) {
        float pre = acc + params[(size_t)(l * W_ + row) * RS_ + NTOT_];
        float v = (l == NL_ - 1) ? pre : pre / (1.f + __expf(-pre));
        outv[row] = v;
    }
}

extern "C" void kernel_launch(void* const* d_in, const int* in_sizes, int n_in,
                              void* d_out, int out_size, void* d_ws, size_t ws_size,
                              hipStream_t stream) {
    const float* x      = (const float*)d_in[0];
    const float* params = (const float*)d_in[1];
    // d_in[2] = adj (bool): fixed layered-DAG structure, baked into indexing.
    float* out = (float*)d_out;
    float* ws  = (float*)d_ws;   // needs 2*1024 floats = 8 KB

    void* args[] = { (void*)&x, (void*)&params, (void*)&out, (void*)&ws };
    hipError_t err = hipLaunchCooperativeKernel((void*)mlp_fused,
                                                dim3(256), dim3(256),
                                                args, 0, stream);
    if (err != hipSuccess) {
        // sequential per-layer fallback (7 graph nodes)
        float* buf0 = ws;
        float* buf1 = ws + W_;
        hipLaunchKernelGGL(init_vals, dim3(4), dim3(256), 0, stream, x, buf0);
        const float* cur = buf0;
        for (int l = 1; l < NL_; ++l) {
            float* dst = (l == NL_ - 1) ? out : ((cur == buf0) ? buf1 : buf0);
            hipLaunchKernelGGL(mlp_layer, dim3(256), dim3(256), 0, stream,
                               params, cur, dst, l);
            cur = dst;
        }
    }
}

// Round 2
// 497.717 us; speedup vs baseline: 1.2137x; 1.2137x over previous
//
#include <hip/hip_runtime.h>
#include <hip/hip_cooperative_groups.h>
#include <math.h>

// Problem constants (fixed by the reference):
#define W_    1024              // layer width
#define NL_   8                 // layers (7 matvecs)
#define NTOT_ (W_ * NL_)        // 8192
#define RS_   (NTOT_ + 1)       // params row stride = 8193 floats (bias col 8192)
#define NBLK  256               // 1 block/CU

// ws layout (floats): [0..1023]=buf0, [1024..2047]=buf1,
// [2048]=barrier counter, [2080]=barrier generation (128 B apart).
#define WS_BARRIER_OFF 2048

// Hand-rolled grid barrier: centralized sense-reversing, device-scope atomics.
// cg::grid.sync() measured ~25 us/sync (R1: VALUBusy 0.3%, 205 us total);
// this should be ~1-3 us. Requires co-residency (cooperative launch).
__device__ __forceinline__ void grid_barrier(unsigned* counter, unsigned* gen) {
    __syncthreads();                       // all block stores done
    if (threadIdx.x == 0) {
        unsigned g = __hip_atomic_load(gen, __ATOMIC_RELAXED, __HIP_MEMORY_SCOPE_AGENT);
        __threadfence();                   // release: publish activation stores
        unsigned arrived = __hip_atomic_fetch_add(counter, 1u, __ATOMIC_ACQ_REL,
                                                  __HIP_MEMORY_SCOPE_AGENT);
        if (arrived == NBLK - 1) {
            // last arriver: reset counter, then release new generation
            __hip_atomic_store(counter, 0u, __ATOMIC_RELAXED, __HIP_MEMORY_SCOPE_AGENT);
            __hip_atomic_store(gen, g + 1u, __ATOMIC_RELEASE, __HIP_MEMORY_SCOPE_AGENT);
        } else {
            while (__hip_atomic_load(gen, __ATOMIC_RELAXED, __HIP_MEMORY_SCOPE_AGENT) == g)
                __builtin_amdgcn_s_sleep(1);   // ~64 cyc backoff
        }
        __threadfence();                   // acquire: invalidate L1 for fresh reads
    }
    __syncthreads();
}

// Persistent cooperative kernel, 256 blocks x 256 threads (1 block/CU,
// 1 wave/SIMD -> VGPR budget ~512/wave, so we can hold ALL weights in regs).
__global__ __launch_bounds__(256, 1)
void mlp_fused(const float* __restrict__ x, const float* __restrict__ params,
               float* __restrict__ out, float* __restrict__ ws) {
    __shared__ float h[W_];
    const int tid  = threadIdx.x;
    const int lane = tid & 63;
    const int wave = tid >> 6;                 // 0..3
    const int row  = blockIdx.x * 4 + wave;    // 0..1023

    unsigned* counter = (unsigned*)(ws + WS_BARRIER_OFF);
    unsigned* gen     = (unsigned*)(ws + WS_BARRIER_OFF + 32);
    float* bufs[2] = { ws, ws + W_ };          // ping-pong activations

    // ---- stage layer-1 activations straight from x (no init barrier) ----
    // issue these FIRST so the ds_write's vmcnt wait doesn't cover the
    // 112 weight loads issued below.
    float xv[4];
#pragma unroll
    for (int i = 0; i < 4; ++i) xv[i] = x[tid + 256 * i];

    // ---- prefetch ALL 7 layers' weight row-segments into registers ----
    // lane i covers cols i, i+64, ..., i+960 (coalesced 256 B/wave/load).
    // In-order vmem completion => layer l's FMAs wait only on its own 16
    // loads; later layers' loads drain during barrier waits.
    float w[NL_ - 1][16];
    float b[NL_ - 1];
#pragma unroll
    for (int l = 1; l < NL_; ++l) {
        const float* wrow = params + (size_t)(l * W_ + row) * RS_
                                   + (size_t)(l - 1) * W_ + lane;
#pragma unroll
        for (int i = 0; i < 16; ++i)
            w[l - 1][i] = wrow[64 * i];
        b[l - 1] = params[(size_t)(l * W_ + row) * RS_ + NTOT_];  // bias (bcast)
    }

#pragma unroll
    for (int i = 0; i < 4; ++i) h[tid + 256 * i] = xv[i];
    __syncthreads();

#pragma unroll
    for (int l = 1; l < NL_; ++l) {
        if (l > 1) {
            grid_barrier(counter, gen);        // publishes prev layer + guards h
            const float* cur = bufs[l & 1];    // l=2 reads buf0, l=3 buf1, ...
#pragma unroll
            for (int i = 0; i < 4; ++i) h[tid + 256 * i] = cur[tid + 256 * i];
            __syncthreads();
        }
        float acc = 0.f;
#pragma unroll
        for (int i = 0; i < 16; ++i)
            acc += w[l - 1][i] * h[lane + 64 * i];   // LDS stride-64: 2-way alias, free
#pragma unroll
        for (int off = 32; off; off >>= 1)
            acc += __shfl_down(acc, off);
        if (lane == 0) {
            float pre = acc + b[l - 1];
            if (l == NL_ - 1) out[row] = pre;                       // identity
            else bufs[(l - 1) & 1][row] = pre / (1.f + __expf(-pre)); // silu
        }
    }
}

// ---- fallback path (only if cooperative launch is rejected) ----
__global__ void init_vals(const float* __restrict__ x, float* __restrict__ buf) {
    int g = blockIdx.x * blockDim.x + threadIdx.x;
    if (g < W_) buf[g] = x[g];
}

__global__ __launch_bounds__(256)
void mlp_layer(const float* __restrict__ params, const float* __restrict__ in,
               float* __restrict__ outv, int l) {
    __shared__ float h[W_];
    const int tid  = threadIdx.x;
    const int lane = tid & 63;
    const int wave = tid >> 6;
    const int row  = blockIdx.x * 4 + wave;
#pragma unroll
    for (int i = 0; i < W_ / 256; ++i)
        h[tid + 256 * i] = in[tid + 256 * i];
    __syncthreads();
    const float* wrow = params + (size_t)(l * W_ + row) * RS_ + (size_t)(l - 1) * W_;
    float acc = 0.f;
#pragma unroll
    for (int i = 0; i < 16; ++i)
        acc += wrow[lane + 64 * i] * h[lane + 64 * i];
#pragma unroll
    for (int off = 32; off; off >>= 1)
        acc += __shfl_down(acc, off);
    if (lane == 0) {
        float pre = acc + params[(size_t)(l * W_ + row) * RS_ + NTOT_];
        float v = (l == NL_ - 1) ? pre : pre / (1.f + __expf(-pre));
        outv[row] = v;
    }
}

extern "C" void kernel_launch(void* const* d_in, const int* in_sizes, int n_in,
                              void* d_out, int out_size, void* d_ws, size_t ws_size,
                              hipStream_t stream) {
    const float* x      = (const float*)d_in[0];
    const float* params = (const float*)d_in[1];
    // d_in[2] = adj (bool): fixed layered-DAG structure, baked into indexing.
    float* out = (float*)d_out;
    float* ws  = (float*)d_ws;

    // zero the barrier state (ws is re-poisoned 0xAA before every call)
    hipMemsetAsync(ws + WS_BARRIER_OFF, 0, 256, stream);

    void* args[] = { (void*)&x, (void*)&params, (void*)&out, (void*)&ws };
    hipError_t err = hipLaunchCooperativeKernel((void*)mlp_fused,
                                                dim3(NBLK), dim3(256),
                                                args, 0, stream);
    if (err != hipSuccess) {
        // sequential per-layer fallback (7 graph nodes)
        float* buf0 = ws;
        float* buf1 = ws + W_;
        hipLaunchKernelGGL(init_vals, dim3(4), dim3(256), 0, stream, x, buf0);
        const float* cur = buf0;
        for (int l = 1; l < NL_; ++l) {
            float* dst = (l == NL_ - 1) ? out : ((cur == buf0) ? buf1 : buf0);
            hipLaunchKernelGGL(mlp_layer, dim3(256), dim3(256), 0, stream,
                               params, cur, dst, l);
            cur = dst;
        }
    }
}

// Round 3
// 477.221 us; speedup vs baseline: 1.2658x; 1.0429x over previous
//
#include <hip/hip_runtime.h>
#include <hip/hip_cooperative_groups.h>
#include <math.h>

// Problem constants (fixed by the reference):
#define W_    1024              // layer width
#define NL_   8                 // layers (7 matvecs)
#define NTOT_ (W_ * NL_)        // 8192
#define RS_   (NTOT_ + 1)       // params row stride = 8193 floats (bias col 8192)
#define NBLK  256               // 1 block/CU

// ws layout (floats): [0..1023]=buf0, [1024..2047]=buf1,
// flags at float-offset 4096: unsigned flags[6][256] (layers 1..6 arrivals).
#define FLAGS_OFF 4096

__device__ __forceinline__ float ld_bypass(const float* p) {
    // agent-scope relaxed atomic load: sc0+sc1 -> bypasses L1 and (non-coherent
    // cross-XCD) L2, reads the MALL/memory coherence point.
    return __hip_atomic_load(p, __ATOMIC_RELAXED, __HIP_MEMORY_SCOPE_AGENT);
}
__device__ __forceinline__ void st_bypass(float* p, float v) {
    __hip_atomic_store(p, v, __ATOMIC_RELAXED, __HIP_MEMORY_SCOPE_AGENT);
}

// Persistent cooperative kernel, 256 blocks x 256 threads, 1 block/CU.
// Inter-layer sync: flat per-block flag arrays (no centralized RMW counter —
// R2's 256-serialized atomicAdd barrier cost ~11-15 us/sync).
__global__ __launch_bounds__(256, 1)
void mlp_fused(const float* __restrict__ x, const float* __restrict__ params,
               float* __restrict__ out, float* __restrict__ ws) {
    __shared__ float h[W_];
    const int tid  = threadIdx.x;
    const int lane = tid & 63;
    const int wave = tid >> 6;                 // 0..3
    const int row  = blockIdx.x * 4 + wave;    // 0..1023

    unsigned* flags = (unsigned*)(ws + FLAGS_OFF);   // [6][256], zeroed by memset
    float* bufs[2] = { ws, ws + W_ };                // ping-pong activations

    // Biases for all 7 layers (wave-uniform loads, drained by first barrier).
    float bias[NL_ - 1];
#pragma unroll
    for (int l = 1; l < NL_; ++l)
        bias[l - 1] = params[(size_t)(l * W_ + row) * RS_ + NTOT_];

    // Double-buffered weight rows: wreg[(l-1)&1] holds layer l's 16 segments.
    // lane i covers cols i, i+64, ..., i+960 (coalesced 256 B/wave/load).
    float wreg[2][16];
    {
        const float* wrow = params + (size_t)(1 * W_ + row) * RS_ + 0 * W_ + lane;
#pragma unroll
        for (int i = 0; i < 16; ++i) wreg[0][i] = wrow[64 * i];
    }

    // Stage layer-1 input straight from x.
    float xv[4];
#pragma unroll
    for (int i = 0; i < 4; ++i) xv[i] = x[tid + 256 * i];
#pragma unroll
    for (int i = 0; i < 4; ++i) h[tid + 256 * i] = xv[i];
    __syncthreads();   // drains this wave's vmem: x, biases, layer-1 weights

#pragma unroll
    for (int l = 1; l < NL_; ++l) {
        const int pb = (l - 1) & 1;            // weight bank for this layer

        if (l > 1) {
            // ---- wait: all 256 producer blocks of layer l-1 arrived ----
            const unsigned* flg = flags + (size_t)(l - 2) * 256;
            unsigned f;
            do {
                f = __hip_atomic_load(flg + tid, __ATOMIC_RELAXED,
                                      __HIP_MEMORY_SCOPE_AGENT);
            } while (!__syncthreads_and((int)(f != 0)));
            // (each poll round = ONE coalesced 1KB load per wave + barrier;
            //  its vmcnt wait also drains this layer's weight prefetch — needed now)

            // ---- stage activations (bypass loads: always coherence-point fresh) ----
            const float* cur = bufs[l & 1];    // l=2 reads buf0, l=3 buf1, ...
            float hv[4];
#pragma unroll
            for (int i = 0; i < 4; ++i) hv[i] = ld_bypass(cur + tid + 256 * i);
#pragma unroll
            for (int i = 0; i < 4; ++i) h[tid + 256 * i] = hv[i];
            __syncthreads();
        }

        // ---- dot: LDS stride-64 (2-way alias, free) x registered weights ----
        float acc = 0.f;
#pragma unroll
        for (int i = 0; i < 16; ++i)
            acc += wreg[pb][i] * h[lane + 64 * i];
#pragma unroll
        for (int off = 32; off; off >>= 1)
            acc += __shfl_down(acc, off);

        if (lane == 0) {
            float pre = acc + bias[l - 1];
            if (l == NL_ - 1) out[row] = pre;                        // identity
            else st_bypass(bufs[(l - 1) & 1] + row,
                           pre / (1.f + __expf(-pre)));              // silu
        }

        if (l < NL_ - 1) {
            // ---- arrive: one release flag store per block, no RMW ----
            __syncthreads();   // per-wave vmcnt drain => all 4 act stores done
            if (tid == 0)
                __hip_atomic_store(flags + (size_t)(l - 1) * 256 + blockIdx.x,
                                   1u, __ATOMIC_RELEASE, __HIP_MEMORY_SCOPE_AGENT);
            // ---- rolling prefetch: layer l+1 weights drain during handoff ----
            if (l < NL_ - 2 + 1) {   // l+1 <= 7
                const float* wrow = params + (size_t)((l + 1) * W_ + row) * RS_
                                           + (size_t)l * W_ + lane;
#pragma unroll
                for (int i = 0; i < 16; ++i) wreg[l & 1][i] = wrow[64 * i];
            }
        }
    }
}

// ---- fallback path (only if cooperative launch is rejected) ----
__global__ void init_vals(const float* __restrict__ x, float* __restrict__ buf) {
    int g = blockIdx.x * blockDim.x + threadIdx.x;
    if (g < W_) buf[g] = x[g];
}

__global__ __launch_bounds__(256)
void mlp_layer(const float* __restrict__ params, const float* __restrict__ in,
               float* __restrict__ outv, int l) {
    __shared__ float h[W_];
    const int tid  = threadIdx.x;
    const int lane = tid & 63;
    const int wave = tid >> 6;
    const int row  = blockIdx.x * 4 + wave;
#pragma unroll
    for (int i = 0; i < W_ / 256; ++i)
        h[tid + 256 * i] = in[tid + 256 * i];
    __syncthreads();
    const float* wrow = params + (size_t)(l * W_ + row) * RS_ + (size_t)(l - 1) * W_;
    float acc = 0.f;
#pragma unroll
    for (int i = 0; i < 16; ++i)
        acc += wrow[lane + 64 * i] * h[lane + 64 * i];
#pragma unroll
    for (int off = 32; off; off >>= 1)
        acc += __shfl_down(acc, off);
    if (lane == 0) {
        float pre = acc + params[(size_t)(l * W_ + row) * RS_ + NTOT_];
        float v = (l == NL_ - 1) ? pre : pre / (1.f + __expf(-pre));
        outv[row] = v;
    }
}

extern "C" void kernel_launch(void* const* d_in, const int* in_sizes, int n_in,
                              void* d_out, int out_size, void* d_ws, size_t ws_size,
                              hipStream_t stream) {
    const float* x      = (const float*)d_in[0];
    const float* params = (const float*)d_in[1];
    // d_in[2] = adj (bool): fixed layered-DAG structure, baked into indexing.
    float* out = (float*)d_out;
    float* ws  = (float*)d_ws;

    // zero the 6x256 flag dwords (ws is re-poisoned 0xAA before every call)
    hipMemsetAsync(ws + FLAGS_OFF, 0, 6 * 256 * sizeof(unsigned), stream);

    void* args[] = { (void*)&x, (void*)&params, (void*)&out, (void*)&ws };
    hipError_t err = hipLaunchCooperativeKernel((void*)mlp_fused,
                                                dim3(NBLK), dim3(256),
                                                args, 0, stream);
    if (err != hipSuccess) {
        // sequential per-layer fallback (7 graph nodes)
        float* buf0 = ws;
        float* buf1 = ws + W_;
        hipLaunchKernelGGL(init_vals, dim3(4), dim3(256), 0, stream, x, buf0);
        const float* cur = buf0;
        for (int l = 1; l < NL_; ++l) {
            float* dst = (l == NL_ - 1) ? out : ((cur == buf0) ? buf1 : buf0);
            hipLaunchKernelGGL(mlp_layer, dim3(256), dim3(256), 0, stream,
                               params, cur, dst, l);
            cur = dst;
        }
    }
}

// Round 4
// 445.684 us; speedup vs baseline: 1.3554x; 1.0708x over previous
//
#include <hip/hip_runtime.h>
#include <math.h>

// Problem constants (fixed by the reference):
#define W_    1024              // layer width
#define NL_   8                 // layers (7 matvecs)
#define NTOT_ (W_ * NL_)        // 8192
#define RS_   (NTOT_ + 1)       // params row stride = 8193 floats (bias col 8192)
#define NBLK  256               // 1 block/CU

typedef unsigned long long u64;

// Relaxed agent-scope 8B atomics: single global_load/store_dwordx2 with
// sc0+sc1 (bypass L1 + non-coherent L2, performed at MALL). No buffer_wbl2 /
// buffer_inv cache maintenance (that was R3's RELEASE-store cost).
__device__ __forceinline__ u64 ld64(const u64* p) {
    return __hip_atomic_load(p, __ATOMIC_RELAXED, __HIP_MEMORY_SCOPE_AGENT);
}
__device__ __forceinline__ void st64(u64* p, u64 v) {
    __hip_atomic_store(p, v, __ATOMIC_RELAXED, __HIP_MEMORY_SCOPE_AGENT);
}
__device__ __forceinline__ u64 pack(int tag, float v) {
    return ((u64)(unsigned)tag << 32) | (u64)__float_as_uint(v);
}

// Persistent cooperative kernel, 256 blocks x 256 threads, 1 block/CU.
// Inter-layer handoff is pure dataflow: each activation is published as a
// packed (layer_tag, value) 8B atomic; consumers poll the 4 values they need.
// One one-way trip + poll detect per layer — no flags, no barrier, no
// release/acquire. 0xAA pre-poison of ws == tag 0xAAAAAAAA, never a valid
// layer tag, so no memset is required.
__global__ __launch_bounds__(256, 1)
void mlp_fused(const float* __restrict__ x, const float* __restrict__ params,
               float* __restrict__ out, float* __restrict__ ws) {
    __shared__ float h[W_];
    const int tid  = threadIdx.x;
    const int lane = tid & 63;
    const int wave = tid >> 6;                 // 0..3
    const int row  = blockIdx.x * 4 + wave;    // 0..1023

    u64* bufs[2] = { (u64*)ws, (u64*)ws + W_ };   // ping-pong packed activations

    // Biases for layers 1..7 (wave-uniform loads; complete whenever).
    float bias[NL_ - 1];
#pragma unroll
    for (int l = 1; l < NL_; ++l)
        bias[l - 1] = params[(size_t)(l * W_ + row) * RS_ + NTOT_];

    // Double-buffered weight rows: wreg[(l-1)&1] holds layer l's 16 segments.
    // lane i covers cols i, i+64, ..., i+960 (coalesced 256 B/wave/load).
    float wreg[2][16];
    {
        const float* wrow = params + (size_t)(1 * W_ + row) * RS_ + lane;
#pragma unroll
        for (int i = 0; i < 16; ++i) wreg[0][i] = wrow[64 * i];
    }

    // Stage layer-1 input straight from x.
#pragma unroll
    for (int i = 0; i < 4; ++i) h[tid + 256 * i] = x[tid + 256 * i];
    __syncthreads();

#pragma unroll
    for (int l = 1; l < NL_; ++l) {
        if (l > 1) {
            // ---- dataflow wait: poll MY 4 packed activations of layer l-1 ----
            const u64* cur = bufs[l & 1];      // l=2 reads buf0, l=3 buf1, ...
            const u64 want = (u64)(unsigned)(l - 1);
            u64 u0, u1, u2, u3;
            do {                               // 4 loads in flight per round
                u0 = ld64(cur + tid);
                u1 = ld64(cur + tid + 256);
                u2 = ld64(cur + tid + 512);
                u3 = ld64(cur + tid + 768);
            } while (((u0 >> 32) != want) | ((u1 >> 32) != want) |
                     ((u2 >> 32) != want) | ((u3 >> 32) != want));
            h[tid]       = __uint_as_float((unsigned)u0);
            h[tid + 256] = __uint_as_float((unsigned)u1);
            h[tid + 512] = __uint_as_float((unsigned)u2);
            h[tid + 768] = __uint_as_float((unsigned)u3);
            __syncthreads();   // ALL block reads of layer l-1 done before any
                               // publish below => ping-pong reuse is race-free
        }

        // ---- rolling prefetch: layer l+1 weights drain during this layer's
        //      dot + publish + next handoff wait (detect = max, not sum) ----
        if (l < NL_ - 1) {
            const float* wrow = params + (size_t)((l + 1) * W_ + row) * RS_
                                       + (size_t)l * W_ + lane;
#pragma unroll
            for (int i = 0; i < 16; ++i) wreg[l & 1][i] = wrow[64 * i];
        }

        // ---- dot: LDS stride-64 (2-way alias, free) x registered weights ----
        float acc = 0.f;
#pragma unroll
        for (int i = 0; i < 16; ++i)
            acc += wreg[(l - 1) & 1][i] * h[lane + 64 * i];
#pragma unroll
        for (int off = 32; off; off >>= 1)
            acc += __shfl_down(acc, off);

        if (lane == 0) {
            float pre = acc + bias[l - 1];
            if (l == NL_ - 1) out[row] = pre;                 // identity
            else {
                float v = pre / (1.f + __expf(-pre));         // silu
                st64(bufs[(l - 1) & 1] + row, pack(l, v));    // publish (tag+data)
            }
        }
    }
}

// ---- fallback path (only if cooperative launch is rejected) ----
__global__ void init_vals(const float* __restrict__ x, float* __restrict__ buf) {
    int g = blockIdx.x * blockDim.x + threadIdx.x;
    if (g < W_) buf[g] = x[g];
}

__global__ __launch_bounds__(256)
void mlp_layer(const float* __restrict__ params, const float* __restrict__ in,
               float* __restrict__ outv, int l) {
    __shared__ float h[W_];
    const int tid  = threadIdx.x;
    const int lane = tid & 63;
    const int wave = tid >> 6;
    const int row  = blockIdx.x * 4 + wave;
#pragma unroll
    for (int i = 0; i < W_ / 256; ++i)
        h[tid + 256 * i] = in[tid + 256 * i];
    __syncthreads();
    const float* wrow = params + (size_t)(l * W_ + row) * RS_ + (size_t)(l - 1) * W_;
    float acc = 0.f;
#pragma unroll
    for (int i = 0; i < 16; ++i)
        acc += wrow[lane + 64 * i] * h[lane + 64 * i];
#pragma unroll
    for (int off = 32; off; off >>= 1)
        acc += __shfl_down(acc, off);
    if (lane == 0) {
        float pre = acc + params[(size_t)(l * W_ + row) * RS_ + NTOT_];
        float v = (l == NL_ - 1) ? pre : pre / (1.f + __expf(-pre));
        outv[row] = v;
    }
}

extern "C" void kernel_launch(void* const* d_in, const int* in_sizes, int n_in,
                              void* d_out, int out_size, void* d_ws, size_t ws_size,
                              hipStream_t stream) {
    const float* x      = (const float*)d_in[0];
    const float* params = (const float*)d_in[1];
    // d_in[2] = adj (bool): fixed layered-DAG structure, baked into indexing.
    float* out = (float*)d_out;
    float* ws  = (float*)d_ws;   // 16 KB used: 2 x 1024 packed u64 activations

    void* args[] = { (void*)&x, (void*)&params, (void*)&out, (void*)&ws };
    hipError_t err = hipLaunchCooperativeKernel((void*)mlp_fused,
                                                dim3(NBLK), dim3(256),
                                                args, 0, stream);
    if (err != hipSuccess) {
        // sequential per-layer fallback (7 graph nodes)
        float* buf0 = ws;
        float* buf1 = ws + W_;
        hipLaunchKernelGGL(init_vals, dim3(4), dim3(256), 0, stream, x, buf0);
        const float* cur = buf0;
        for (int l = 1; l < NL_; ++l) {
            float* dst = (l == NL_ - 1) ? out : ((cur == buf0) ? buf1 : buf0);
            hipLaunchKernelGGL(mlp_layer, dim3(256), dim3(256), 0, stream,
                               params, cur, dst, l);
            cur = dst;
        }
    }
}

// Round 5
// 411.400 us; speedup vs baseline: 1.4684x; 1.0833x over previous
//
#include <hip/hip_runtime.h>
#include <math.h>

// Problem constants (fixed by the reference):
#define W_    1024              // layer width
#define NL_   8                 // layers (7 matvecs)
#define NTOT_ (W_ * NL_)        // 8192
#define RS_   (NTOT_ + 1)       // params row stride = 8193 floats (bias col 8192)
#define NBLK  256               // 1 block/CU

typedef unsigned long long u64;

// Relaxed agent-scope 8B atomics: single global_load/store_dwordx2 with
// sc0+sc1 (bypass L1 + non-coherent L2, performed at MALL coherence point).
__device__ __forceinline__ u64 ld64(const u64* p) {
    return __hip_atomic_load(p, __ATOMIC_RELAXED, __HIP_MEMORY_SCOPE_AGENT);
}
__device__ __forceinline__ void st64(u64* p, u64 v) {
    __hip_atomic_store(p, v, __ATOMIC_RELAXED, __HIP_MEMORY_SCOPE_AGENT);
}
__device__ __forceinline__ u64 pack(int tag, float v) {
    return ((u64)(unsigned)tag << 32) | (u64)__float_as_uint(v);
}

// Persistent kernel, 256 blocks x 256 threads, 1 block/CU.
// PLAIN launch (no cooperative): with 1024 waves total vs 8192-wave device
// capacity, the HW distributor makes every block resident immediately —
// no block ever waits on another block's completion to be dispatched, so the
// spin-wait dataflow cannot deadlock. (Cooperative graph nodes carried
// per-replay overhead; no grid.sync() has existed since R3.)
//
// Inter-layer handoff is pure dataflow: each activation is published as a
// packed (layer_tag, value) 8B atomic; consumers poll the 4 values they need.
// One one-way store + poll detect per layer — no flags, no barriers, no
// release/acquire cache maintenance. ws's 0xAA pre-poison (tag 0xAAAAAAAA)
// never equals a valid layer tag 1..6, so no memset is needed.
//
// Ping-pong reuse (layer l+2 overwrites layer l's buffer) is race-free:
// every block reads ALL 1024 values of a layer before publishing its own
// rows of the next — so any layer-(l+2) publish happens-after every block
// finished reading layer l (each layer is a de-facto full barrier).
__global__ __launch_bounds__(256, 1)
void mlp_fused(const float* __restrict__ x, const float* __restrict__ params,
               float* __restrict__ out, float* __restrict__ ws) {
    __shared__ float h[W_];
    const int tid  = threadIdx.x;
    const int lane = tid & 63;
    const int wave = tid >> 6;                 // 0..3
    const int row  = blockIdx.x * 4 + wave;    // 0..1023

    u64* bufs[2] = { (u64*)ws, (u64*)ws + W_ };   // ping-pong packed activations

    // Biases for layers 1..7 (wave-uniform loads; complete whenever).
    float bias[NL_ - 1];
#pragma unroll
    for (int l = 1; l < NL_; ++l)
        bias[l - 1] = params[(size_t)(l * W_ + row) * RS_ + NTOT_];

    // Double-buffered weight rows: wreg[(l-1)&1] holds layer l's 16 segments.
    // lane i covers cols i, i+64, ..., i+960 (coalesced 256 B/wave/load).
    float wreg[2][16];
    {
        const float* wrow = params + (size_t)(1 * W_ + row) * RS_ + lane;
#pragma unroll
        for (int i = 0; i < 16; ++i) wreg[0][i] = wrow[64 * i];
    }

    // Stage layer-1 input straight from x.
#pragma unroll
    for (int i = 0; i < 4; ++i) h[tid + 256 * i] = x[tid + 256 * i];
    __syncthreads();

#pragma unroll
    for (int l = 1; l < NL_; ++l) {
        // ---- rolling prefetch, issued BEFORE this layer's poll: the 16
        //      loads for layer l+1 drain during the handoff wait (the first
        //      poll round's vmcnt wait absorbs them off the critical path) ----
        if (l < NL_ - 1) {
            const float* wrow = params + (size_t)((l + 1) * W_ + row) * RS_
                                       + (size_t)l * W_ + lane;
#pragma unroll
            for (int i = 0; i < 16; ++i) wreg[l & 1][i] = wrow[64 * i];
        }

        if (l > 1) {
            // ---- dataflow wait: poll MY 4 packed activations of layer l-1 ----
            const u64* cur = bufs[l & 1];      // l=2 reads buf0, l=3 buf1, ...
            const u64 want = (u64)(unsigned)(l - 1);
            u64 u0, u1, u2, u3;
            do {                               // 4 loads in flight per round
                u0 = ld64(cur + tid);
                u1 = ld64(cur + tid + 256);
                u2 = ld64(cur + tid + 512);
                u3 = ld64(cur + tid + 768);
            } while (((u0 >> 32) != want) | ((u1 >> 32) != want) |
                     ((u2 >> 32) != want) | ((u3 >> 32) != want));
            h[tid]       = __uint_as_float((unsigned)u0);
            h[tid + 256] = __uint_as_float((unsigned)u1);
            h[tid + 512] = __uint_as_float((unsigned)u2);
            h[tid + 768] = __uint_as_float((unsigned)u3);
            __syncthreads();   // all block reads of layer l-1 done before any
                               // publish below => ping-pong reuse is race-free
        }

        // ---- dot: LDS stride-64 (2-way alias, free) x registered weights ----
        float acc = 0.f;
#pragma unroll
        for (int i = 0; i < 16; ++i)
            acc += wreg[(l - 1) & 1][i] * h[lane + 64 * i];
#pragma unroll
        for (int off = 32; off; off >>= 1)
            acc += __shfl_down(acc, off);

        if (lane == 0) {
            float pre = acc + bias[l - 1];
            if (l == NL_ - 1) out[row] = pre;                 // identity
            else {
                float v = pre / (1.f + __expf(-pre));         // silu
                st64(bufs[(l - 1) & 1] + row, pack(l, v));    // publish (tag+data)
            }
        }
    }
}

extern "C" void kernel_launch(void* const* d_in, const int* in_sizes, int n_in,
                              void* d_out, int out_size, void* d_ws, size_t ws_size,
                              hipStream_t stream) {
    const float* x      = (const float*)d_in[0];
    const float* params = (const float*)d_in[1];
    // d_in[2] = adj (bool): fixed layered-DAG structure, baked into indexing.
    float* out = (float*)d_out;
    float* ws  = (float*)d_ws;   // 16 KB used: 2 x 1024 packed u64 activations

    hipLaunchKernelGGL(mlp_fused, dim3(NBLK), dim3(256), 0, stream,
                       x, params, out, ws);
}